// Round 5
// baseline (1088.240 us; speedup 1.0000x reference)
//
#include <hip/hip_runtime.h>
#include <cstdint>

// B=16, S=2048, E=512, H=1024. Inputs fp32; OUTPUT fp32.
// R5: (1) ffn_ln3: chunk 256->64, single-buffered ldsH with LN3-sum alias
// -> LDS 72KB -> 2 blocks/CU (4 waves/SIMD, was 1 blk / 2 w/SIMD): the
// R0/R3/R4-invariant ~300us FFN cost is latency at min occupancy. W2 frags
// prefetched to regs before the h barrier. (2) attn: barrier D = lgkm-only
// (K-stage vmcnt drain moved to barrier G; load structure/order unchanged —
// R2 lesson) + T13 defer-max (THR=8, exact): skip oacc rescale when max
// stable; per-wave flag, PV branches per-qg (uniform).
// Falsifier: attn FETCH_SIZE must stay ~339MB; >380MB -> revert barrier D.
#define B_ 16
#define S_ 2048
#define E_ 512
#define H_ 1024
#define SCALE 0.044194173824159216f   // 1/sqrt(512)
#define KVB 32
#define NTILES 64                     // S_/KVB

typedef __attribute__((ext_vector_type(8))) short short8;    // 8 bf16 (4 VGPRs)
typedef __attribute__((ext_vector_type(4))) float floatx4;

static __device__ __forceinline__ unsigned short f2bf(float f) {
    unsigned u = __float_as_uint(f);
    u = u + 0x7FFFu + ((u >> 16) & 1u);   // RNE
    return (unsigned short)(u >> 16);
}
static __device__ __forceinline__ float bf2f(unsigned short h) {
    return __uint_as_float(((unsigned)h) << 16);
}

// ---------------- elementwise fp32 -> bf16 ----------------
__global__ void cvt_f32_bf16(const float* __restrict__ in, unsigned short* __restrict__ out, int n8) {
    int i = blockIdx.x * blockDim.x + threadIdx.x;
    if (i >= n8) return;
    const float4* p = (const float4*)in + (long)i * 2;
    float4 a = p[0], b = p[1];
    union { unsigned short u[8]; uint4 v; } r;
    r.u[0] = f2bf(a.x); r.u[1] = f2bf(a.y); r.u[2] = f2bf(a.z); r.u[3] = f2bf(a.w);
    r.u[4] = f2bf(b.x); r.u[5] = f2bf(b.y); r.u[6] = f2bf(b.z); r.u[7] = f2bf(b.w);
    ((uint4*)out)[i] = r.v;
}

// ---------------- tiled transpose + convert: fp32 [R][C] -> bf16 [C][R] ----------------
__global__ void transpose_cvt(const float* __restrict__ in, unsigned short* __restrict__ out,
                              int R, int C, long inBS, long outBS) {
    __shared__ float t[64 * 68];
    const int z = blockIdx.z;
    in += (long)z * inBS; out += (long)z * outBS;
    const int c0 = blockIdx.x * 64, r0 = blockIdx.y * 64;
    const int tid = threadIdx.x;
    {
        int col4 = (tid & 15) * 4;
        #pragma unroll
        for (int i = 0; i < 4; i++) {
            int row = (tid >> 4) + i * 16;
            float4 v = *(const float4*)(in + (long)(r0 + row) * C + c0 + col4);
            *(float4*)(&t[row * 68 + col4]) = v;
        }
    }
    __syncthreads();
    {
        int oc = tid >> 2;            // output row (C index), 0..63
        int ob = (tid & 3) * 16;      // output col base (R index)
        union { unsigned short u[16]; uint4 v[2]; } r;
        #pragma unroll
        for (int j = 0; j < 16; j++) r.u[j] = f2bf(t[(ob + j) * 68 + oc]);
        uint4* dst = (uint4*)(out + (long)(c0 + oc) * R + r0 + ob);
        dst[0] = r.v[0]; dst[1] = r.v[1];
    }
}

// ---------------- flash attention + residual + fused LN1 ----------------
// R1 structure; R5 deltas: lgkm-only barrier D, defer-max rescale skip.
__launch_bounds__(256, 2)
__global__ void attn_kernel(const float* __restrict__ q,             // [B][S][E] fp32
                            const unsigned short* __restrict__ kb,   // [B][S][E] bf16
                            const unsigned short* __restrict__ vt,   // [B][E][S] bf16
                            const float* __restrict__ g1,            // ln1 gamma [E] fp32
                            const float* __restrict__ bb1,           // ln1 beta  [E] fp32
                            unsigned short* __restrict__ xb) {       // [B][S][E] bf16 = LN1(q+attn)
    __shared__ unsigned short kLDS[2][KVB * E_];   // 2 x 32KB, swizzled rows
    __shared__ unsigned short pLDS[64 * 40];
    __shared__ float aLDS[64];
    __shared__ int fLDS[4];
    __shared__ float lLDS[64];
    __shared__ float sumLDS[64 * 4];
    __shared__ float sqLDS[64 * 4];
    const int tid = threadIdx.x;
    const int w = tid >> 6, lane = tid & 63, quad = lane >> 4, l16 = lane & 15;
    const int b = blockIdx.x >> 5, q0 = (blockIdx.x & 31) * 64;
    const floatx4 zf = {0.f, 0.f, 0.f, 0.f};

    const unsigned short* kb_b = kb + (long)b * S_ * E_;

    // Q A-frags: A[m=l16][k=quad*8+j], 16 chunks of K=32 over E=512 (fp32 -> bf16)
    short8 aq[16];
    {
        const float* qp = q + (long)(b * S_ + q0 + 16 * w + l16) * E_ + quad * 8;
        #pragma unroll
        for (int kc = 0; kc < 16; kc++) {
            float4 x0 = *(const float4*)(qp + kc * 32);
            float4 x1 = *(const float4*)(qp + kc * 32 + 4);
            short8 t;
            t[0] = (short)f2bf(x0.x); t[1] = (short)f2bf(x0.y);
            t[2] = (short)f2bf(x0.z); t[3] = (short)f2bf(x0.w);
            t[4] = (short)f2bf(x1.x); t[5] = (short)f2bf(x1.y);
            t[6] = (short)f2bf(x1.z); t[7] = (short)f2bf(x1.w);
            aq[kc] = t;
        }
    }

    floatx4 oacc[4][8];   // [qg][nt] : 64q x 128f per wave
    #pragma unroll
    for (int qg = 0; qg < 4; qg++)
        #pragma unroll
        for (int nt = 0; nt < 8; nt++) oacc[qg][nt] = zf;
    float m_[4] = {-INFINITY, -INFINITY, -INFINITY, -INFINITY};
    float l_[4] = {0.f, 0.f, 0.f, 0.f};

    const unsigned short* vbase = vt + (long)(b * E_ + 128 * w + l16) * S_ + quad * 8;

    // prologue: stage K tile 0 into kLDS[0].
    {
        #pragma unroll
        for (int j = 0; j < 8; j++) {
            int row = j * 4 + w;
            const unsigned short* g = kb_b + (long)row * E_ + ((lane * 8) ^ ((row & 7) << 3));
            __builtin_amdgcn_global_load_lds(
                (const __attribute__((address_space(1))) void*)g,
                (__attribute__((address_space(3))) void*)(&kLDS[0][row * E_]), 16, 0, 0);
        }
    }
    __syncthreads();   // vmcnt(0) drain -> tile 0 resident

    for (int t = 0; t < NTILES; t++) {
        const int cur = t & 1;
        const int kt0 = t * KVB;

        // A: issue async stage of tile t+1 into the other buffer (stays in
        // flight across the whole tile; drained at barrier G).
        if (t + 1 < NTILES) {
            const unsigned short* kb_t = kb_b + (long)(kt0 + KVB) * E_;
            #pragma unroll
            for (int j = 0; j < 8; j++) {
                int row = j * 4 + w;
                const unsigned short* g = kb_t + (long)row * E_ + ((lane * 8) ^ ((row & 7) << 3));
                __builtin_amdgcn_global_load_lds(
                    (const __attribute__((address_space(1))) void*)g,
                    (__attribute__((address_space(3))) void*)(&kLDS[cur ^ 1][row * E_]), 16, 0, 0);
            }
        }

        // B: QK^T from kLDS[cur] (swizzled ds_read_b128)
        floatx4 sacc[2] = {zf, zf};
        const unsigned short* kl = &kLDS[cur][0];
        const int swz = (l16 & 7) << 3;
        #pragma unroll
        for (int kc = 0; kc < 16; kc++) {
            const int cx = (kc * 32 + quad * 8) ^ swz;
            short8 b0 = *(const short8*)(kl + l16 * E_ + cx);
            short8 b1 = *(const short8*)(kl + (16 + l16) * E_ + cx);
            sacc[0] = __builtin_amdgcn_mfma_f32_16x16x32_bf16(aq[kc], b0, sacc[0], 0, 0, 0);
            sacc[1] = __builtin_amdgcn_mfma_f32_16x16x32_bf16(aq[kc], b1, sacc[1], 0, 0, 0);
        }

        // C: online softmax with defer-max (T13, exact math).
        float rm[4], al[4], P2[2][4], rs[4];
        #pragma unroll
        for (int r = 0; r < 4; r++)
            rm[r] = fmaxf(sacc[0][r], sacc[1][r]) * SCALE;
        #pragma unroll
        for (int off = 1; off < 16; off <<= 1)
            #pragma unroll
            for (int r = 0; r < 4; r++) rm[r] = fmaxf(rm[r], __shfl_xor(rm[r], off));
        bool resc = __any((rm[0] > m_[0] + 8.f) || (rm[1] > m_[1] + 8.f) ||
                          (rm[2] > m_[2] + 8.f) || (rm[3] > m_[3] + 8.f));
        if (resc) {
            #pragma unroll
            for (int r = 0; r < 4; r++) {
                float mn = fmaxf(m_[r], rm[r]);
                al[r] = __expf(m_[r] - mn);
                m_[r] = mn;
            }
        } else {
            #pragma unroll
            for (int r = 0; r < 4; r++) al[r] = 1.f;
        }
        #pragma unroll
        for (int r = 0; r < 4; r++) {
            float p0 = __expf(sacc[0][r] * SCALE - m_[r]);
            float p1 = __expf(sacc[1][r] * SCALE - m_[r]);
            P2[0][r] = p0; P2[1][r] = p1;
            rs[r] = p0 + p1;
        }
        #pragma unroll
        for (int off = 1; off < 16; off <<= 1)
            #pragma unroll
            for (int r = 0; r < 4; r++) rs[r] += __shfl_xor(rs[r], off);
        #pragma unroll
        for (int r = 0; r < 4; r++) l_[r] = l_[r] * al[r] + rs[r];
        #pragma unroll
        for (int nt = 0; nt < 2; nt++)
            #pragma unroll
            for (int r = 0; r < 4; r++)
                pLDS[(16 * w + quad * 4 + r) * 40 + nt * 16 + l16] = f2bf(P2[nt][r]);
        if (l16 == 0) {
            #pragma unroll
            for (int r = 0; r < 4; r++) aLDS[16 * w + quad * 4 + r] = al[r];
        }
        if (lane == 0) fLDS[w] = resc ? 1 : 0;
        // D: lgkm-only barrier — P/aLDS/fLDS visible; K-stage vmcnt stays in flight.
        asm volatile("s_waitcnt lgkmcnt(0)\n\ts_barrier" ::: "memory");

        // F: PV. P A-frag: A[m=l16][k=quad*8+j] over 32 keys.
        short8 pf[4];
        #pragma unroll
        for (int qg = 0; qg < 4; qg++)
            pf[qg] = *(const short8*)(&pLDS[(qg * 16 + l16) * 40 + quad * 8]);
        #pragma unroll
        for (int qg = 0; qg < 4; qg++) {
            if (fLDS[qg]) {   // wave-uniform per qg
                float av[4];
                #pragma unroll
                for (int r = 0; r < 4; r++) av[r] = aLDS[qg * 16 + quad * 4 + r];
                #pragma unroll
                for (int nt = 0; nt < 8; nt++)
                    #pragma unroll
                    for (int r = 0; r < 4; r++) oacc[qg][nt][r] *= av[r];
            }
        }
        const unsigned short* vtt = vbase + kt0;
        #pragma unroll
        for (int nt = 0; nt < 8; nt++) {
            short8 vf = *(const short8*)(vtt + (long)nt * 16 * S_);
            #pragma unroll
            for (int qg = 0; qg < 4; qg++)
                oacc[qg][nt] = __builtin_amdgcn_mfma_f32_16x16x32_bf16(pf[qg], vf, oacc[qg][nt], 0, 0, 0);
        }
        __syncthreads();   // G: full drain (incl. K-stage vmcnt) + barrier
    }

    // epilogue: y = q + O/l (fp32), fused LN1
    if (l16 == 0) {
        #pragma unroll
        for (int r = 0; r < 4; r++) lLDS[16 * w + quad * 4 + r] = l_[r];
    }
    __syncthreads();
    float lv[4][4];
    #pragma unroll
    for (int qg = 0; qg < 4; qg++)
        #pragma unroll
        for (int r = 0; r < 4; r++) lv[qg][r] = 1.f / lLDS[qg * 16 + quad * 4 + r];
    float ps[4][4], pq2[4][4];
    #pragma unroll
    for (int qg = 0; qg < 4; qg++)
        #pragma unroll
        for (int r = 0; r < 4; r++) { ps[qg][r] = 0.f; pq2[qg][r] = 0.f; }
    #pragma unroll
    for (int qg = 0; qg < 4; qg++)
        #pragma unroll
        for (int nt = 0; nt < 8; nt++)
            #pragma unroll
            for (int r = 0; r < 4; r++) {
                int qrow = q0 + qg * 16 + quad * 4 + r;
                int feat = 128 * w + nt * 16 + l16;
                float y = q[(long)(b * S_ + qrow) * E_ + feat] + oacc[qg][nt][r] * lv[qg][r];
                oacc[qg][nt][r] = y;
                ps[qg][r] += y; pq2[qg][r] += y * y;
            }
    #pragma unroll
    for (int off = 1; off < 16; off <<= 1)
        #pragma unroll
        for (int qg = 0; qg < 4; qg++)
            #pragma unroll
            for (int r = 0; r < 4; r++) {
                ps[qg][r] += __shfl_xor(ps[qg][r], off);
                pq2[qg][r] += __shfl_xor(pq2[qg][r], off);
            }
    if (l16 == 0) {
        #pragma unroll
        for (int qg = 0; qg < 4; qg++)
            #pragma unroll
            for (int r = 0; r < 4; r++) {
                int row = qg * 16 + quad * 4 + r;
                sumLDS[row * 4 + w] = ps[qg][r];
                sqLDS[row * 4 + w] = pq2[qg][r];
            }
    }
    __syncthreads();
    float mu[4][4], rstd[4][4];
    #pragma unroll
    for (int qg = 0; qg < 4; qg++)
        #pragma unroll
        for (int r = 0; r < 4; r++) {
            int row = qg * 16 + quad * 4 + r;
            float s = (sumLDS[row * 4 + 0] + sumLDS[row * 4 + 1]) + (sumLDS[row * 4 + 2] + sumLDS[row * 4 + 3]);
            float s2 = (sqLDS[row * 4 + 0] + sqLDS[row * 4 + 1]) + (sqLDS[row * 4 + 2] + sqLDS[row * 4 + 3]);
            float mean = s * (1.f / E_);
            float var = s2 * (1.f / E_) - mean * mean;
            mu[qg][r] = mean;
            rstd[qg][r] = rsqrtf(fmaxf(var, 0.f) + 1e-5f);
        }
    float gv[8], bv[8];
    #pragma unroll
    for (int nt = 0; nt < 8; nt++) {
        int feat = 128 * w + nt * 16 + l16;
        gv[nt] = g1[feat]; bv[nt] = bb1[feat];
    }
    #pragma unroll
    for (int qg = 0; qg < 4; qg++)
        #pragma unroll
        for (int nt = 0; nt < 8; nt++)
            #pragma unroll
            for (int r = 0; r < 4; r++) {
                int qrow = q0 + qg * 16 + quad * 4 + r;
                int feat = 128 * w + nt * 16 + l16;
                xb[(long)(b * S_ + qrow) * E_ + feat] =
                    f2bf((oacc[qg][nt][r] - mu[qg][r]) * rstd[qg][r] * gv[nt] + bv[nt]);
            }
}

// ---------------- fused FFN + residual + LN3 ----------------
// R5: 64-wide H-chunks (16 chunks), single-buffered ldsH (8KB), LN3 sums
// aliased into ldsH after last chunk -> LDS 72KB -> 2 blocks/CU.
// phase1: wave (mt1=w&3, nh=w>>2) computes h[16 rows][32 cols]; W2 frags
// prefetched to regs pre-barrier; phase2: wave w owns out-cols 64w..64w+63.
__launch_bounds__(512, 4)
__global__ void ffn_ln3_kernel(const unsigned short* __restrict__ X,    // xb [M][512] bf16
                               const unsigned short* __restrict__ W1t,  // [1024][512] bf16
                               const float* __restrict__ b1,            // [1024]
                               const unsigned short* __restrict__ W2t,  // [512][1024] bf16
                               const float* __restrict__ b2,            // [512]
                               const float* __restrict__ g3, const float* __restrict__ bb3,
                               float* __restrict__ Out) {               // [M][512] fp32
    __shared__ unsigned short ldsX[64 * 512];      // 64 KB, swizzled rows
    __shared__ unsigned short ldsH[64 * 64];       // 8 KB, swizzled rows; aliased for LN3 sums at end
    const int tid = threadIdx.x, w = tid >> 6, lane = tid & 63, quad = lane >> 4, l16 = lane & 15;
    const long m0 = (long)blockIdx.x * 64;
    const floatx4 zf = {0.f, 0.f, 0.f, 0.f};
    floatx4 acc2[4][4];   // [mt][nt]: 64 rows x 64 out-cols (n = 64w + nt*16 + l16)
    #pragma unroll
    for (int i = 0; i < 4; i++)
        #pragma unroll
        for (int j = 0; j < 4; j++) acc2[i][j] = zf;

    // stage X_block: wave w stages rows 8w..8w+7 (linear LDS dest, pre-swizzled src)
    #pragma unroll
    for (int j = 0; j < 8; j++) {
        int row = w * 8 + j;
        const unsigned short* g = X + (m0 + row) * 512 + ((lane * 8) ^ ((row & 7) << 3));
        __builtin_amdgcn_global_load_lds(
            (const __attribute__((address_space(1))) void*)g,
            (__attribute__((address_space(3))) void*)(&ldsX[row * 512]), 16, 0, 0);
    }
    __syncthreads();   // X resident

    const int swzx = (l16 & 7) << 3;
    const int mt1 = w & 3, nh = w >> 2;
    for (int c = 0; c < 16; c++) {
        // ---- phase 1: h[16 rows (mt1)][32 cols (nh)] of 64-wide chunk c ----
        floatx4 acc1[2] = {zf, zf};
        const unsigned short* w1p = W1t + (long)(c * 64 + nh * 32 + l16) * 512 + quad * 8;
        #pragma unroll
        for (int kc = 0; kc < 16; kc++) {
            short8 bf0 = *(const short8*)(w1p + kc * 32);
            short8 bf1 = *(const short8*)(w1p + 16 * 512 + kc * 32);
            short8 af = *(const short8*)(&ldsX[(mt1 * 16 + l16) * 512 + ((kc * 32 + quad * 8) ^ swzx)]);
            acc1[0] = __builtin_amdgcn_mfma_f32_16x16x32_bf16(af, bf0, acc1[0], 0, 0, 0);
            acc1[1] = __builtin_amdgcn_mfma_f32_16x16x32_bf16(af, bf1, acc1[1], 0, 0, 0);
        }
        // prefetch this chunk's W2 B-frags (latency hides under barriers + h-write)
        short8 w2f[2][4];
        const unsigned short* w2p = W2t + (long)(64 * w + l16) * 1024 + c * 64 + quad * 8;
        #pragma unroll
        for (int kc = 0; kc < 2; kc++)
            #pragma unroll
            for (int nt = 0; nt < 4; nt++)
                w2f[kc][nt] = *(const short8*)(w2p + (long)nt * 16 * 1024 + kc * 32);
        __syncthreads();   // phase2(c-1) readers of ldsH done
        // write h: rows mt1*16+quad*4+r, cols nh*32+nt*16+l16, XOR-swizzled chunks
        #pragma unroll
        for (int nt = 0; nt < 2; nt++) {
            int cc = nh * 32 + nt * 16 + l16;           // col in chunk, 0..63
            float b1v = b1[c * 64 + cc];
            int c8 = cc >> 3, coff = cc & 7;
            #pragma unroll
            for (int r = 0; r < 4; r++) {
                int row = mt1 * 16 + quad * 4 + r;
                float v = acc1[nt][r] + b1v;
                v = 0.5f * v * (1.f + erff(v * 0.70710678118f));   // exact GELU
                ldsH[row * 64 + (((c8 ^ (row & 7)) << 3) + coff)] = f2bf(v);
            }
        }
        __syncthreads();   // h chunk visible
        // ---- phase 2: acc2 += h_chunk @ W2t slice ----
        #pragma unroll
        for (int kc = 0; kc < 2; kc++) {
            short8 af[4];
            const int hphys = ((kc * 4 + quad) ^ (l16 & 7)) << 3;
            #pragma unroll
            for (int mt = 0; mt < 4; mt++)
                af[mt] = *(const short8*)(&ldsH[(mt * 16 + l16) * 64 + hphys]);
            #pragma unroll
            for (int mt = 0; mt < 4; mt++)
                #pragma unroll
                for (int nt = 0; nt < 4; nt++)
                    acc2[mt][nt] = __builtin_amdgcn_mfma_f32_16x16x32_bf16(af[mt], w2f[kc][nt], acc2[mt][nt], 0, 0, 0);
        }
    }

    // ---- epilogue: v = acc2 + b2 + resid(ldsX); LN3 in-block ----
    float ps[4][4], pq2[4][4];
    #pragma unroll
    for (int mt = 0; mt < 4; mt++)
        #pragma unroll
        for (int r = 0; r < 4; r++) { ps[mt][r] = 0.f; pq2[mt][r] = 0.f; }
    #pragma unroll
    for (int nt = 0; nt < 4; nt++) {
        int n = 64 * w + nt * 16 + l16;
        float bv = b2[n];
        int nc8 = n >> 3, noff = n & 7;
        #pragma unroll
        for (int mt = 0; mt < 4; mt++)
            #pragma unroll
            for (int r = 0; r < 4; r++) {
                int row = mt * 16 + quad * 4 + r;
                float resid = bf2f(ldsX[row * 512 + (((nc8 ^ (row & 7)) << 3) + noff)]);
                float v = acc2[mt][nt][r] + bv + resid;
                acc2[mt][nt][r] = v;
                ps[mt][r] += v; pq2[mt][r] += v * v;
            }
    }
    #pragma unroll
    for (int off = 1; off < 16; off <<= 1)
        #pragma unroll
        for (int mt = 0; mt < 4; mt++)
            #pragma unroll
            for (int r = 0; r < 4; r++) {
                ps[mt][r] += __shfl_xor(ps[mt][r], off);
                pq2[mt][r] += __shfl_xor(pq2[mt][r], off);
            }
    __syncthreads();   // all phase2 reads of ldsH done -> safe to alias sums
    float* sumF = (float*)&ldsH[0];          // [64][8] floats, 2KB
    float* sqF  = (float*)&ldsH[2048];       // byte offset 4096, 2KB
    if (l16 == 0) {
        #pragma unroll
        for (int mt = 0; mt < 4; mt++)
            #pragma unroll
            for (int r = 0; r < 4; r++) {
                int row = mt * 16 + quad * 4 + r;
                sumF[row * 8 + w] = ps[mt][r];
                sqF[row * 8 + w] = pq2[mt][r];
            }
    }
    __syncthreads();
    float mu[4][4], rstd[4][4];
    #pragma unroll
    for (int mt = 0; mt < 4; mt++)
        #pragma unroll
        for (int r = 0; r < 4; r++) {
            int row = mt * 16 + quad * 4 + r;
            float s = 0.f, s2 = 0.f;
            #pragma unroll
            for (int ww = 0; ww < 8; ww++) { s += sumF[row * 8 + ww]; s2 += sqF[row * 8 + ww]; }
            float mean = s * (1.f / E_);
            float var = s2 * (1.f / E_) - mean * mean;
            mu[mt][r] = mean;
            rstd[mt][r] = rsqrtf(fmaxf(var, 0.f) + 1e-5f);
        }
    #pragma unroll
    for (int nt = 0; nt < 4; nt++) {
        int n = 64 * w + nt * 16 + l16;
        float gv = g3[n], bv3 = bb3[n];
        #pragma unroll
        for (int mt = 0; mt < 4; mt++) {
            long m = m0 + mt * 16 + quad * 4;
            #pragma unroll
            for (int r = 0; r < 4; r++)
                Out[(m + r) * E_ + n] =
                    (acc2[mt][nt][r] - mu[mt][r]) * rstd[mt][r] * gv + bv3;
        }
    }
}

extern "C" void kernel_launch(void* const* d_in, const int* in_sizes, int n_in,
                              void* d_out, int out_size, void* d_ws, size_t ws_size,
                              hipStream_t stream) {
    const float* q    = (const float*)d_in[0];
    const float* k    = (const float*)d_in[1];
    const float* v    = (const float*)d_in[2];
    const float* ln1g = (const float*)d_in[3];
    const float* ln1b = (const float*)d_in[4];
    const float* w1   = (const float*)d_in[5];
    const float* b1   = (const float*)d_in[6];
    const float* w2   = (const float*)d_in[7];
    const float* b2   = (const float*)d_in[8];
    const float* ln3g = (const float*)d_in[9];
    const float* ln3b = (const float*)d_in[10];

    // Workspace, 98 MB total (phase-aliased):
    //  [0,32M):   kb  (cvt -> attn)
    //  [32M,64M): vt  (transpose -> attn)
    //  [64M,96M): xb  (attn -> ffn)
    //  [96M,97M): w1t   [97M,98M): w2t
    char* ws = (char*)d_ws;
    unsigned short* kb  = (unsigned short*)(ws);
    unsigned short* vt  = (unsigned short*)(ws + 33554432);
    unsigned short* xb  = (unsigned short*)(ws + 67108864);
    unsigned short* w1t = (unsigned short*)(ws + 100663296);
    unsigned short* w2t = (unsigned short*)(ws + 101711872);
    float* ob = (float*)d_out;                                   // fp32 output

    cvt_f32_bf16<<<8192, 256, 0, stream>>>(k, kb, 2097152);
    transpose_cvt<<<dim3(8, 32, 16), 256, 0, stream>>>(v, vt, 2048, 512, (long)2048 * 512, (long)512 * 2048);
    transpose_cvt<<<dim3(16, 8, 1), 256, 0, stream>>>(w1, w1t, 512, 1024, 0, 0);
    transpose_cvt<<<dim3(8, 16, 1), 256, 0, stream>>>(w2, w2t, 1024, 512, 0, 0);
    attn_kernel<<<512, 256, 0, stream>>>(q, kb, vt, ln1g, ln1b, xb);
    ffn_ln3_kernel<<<512, 512, 0, stream>>>(xb, w1t, b1, w2t, b2, ln3g, ln3b, ob);
}

// Round 6
// 817.444 us; speedup vs baseline: 1.3313x; 1.3313x over previous
//
#include <hip/hip_runtime.h>
#include <cstdint>

// B=16, S=2048, E=512, H=1024. Inputs fp32; OUTPUT fp32.
// R6: consolidate to verified-best (R4 = 807us: attn-R1 + fused ffn-R4) plus
// two surgical fixes:
// (1) attn pLDS stride 40->32 shorts with quad-XOR chunk swizzle
//     (phys = row*32 + ((chunk ^ ((row>>2)&3))<<3) + (col&7)). Bank math:
//     P-writes drop 4-way->2-way (free), pf b128 reads become exactly even
//     over 32 banks. Targets the 18.9M (R1-R5) vs 2.1M (R0) conflict delta.
//     No barrier/load-order change (R2+R5 lesson: barrier discipline frozen).
// (2) prep fused into ONE dispatch (cvt-k + v/w1/w2 transposes) — removes 3
//     sequential launch drains; zero math change.
// Falsifiers: conflicts must drop to ~2-4M else pLDS model wrong (revert);
// FETCH must stay ~339MB.
#define B_ 16
#define S_ 2048
#define E_ 512
#define H_ 1024
#define SCALE 0.044194173824159216f   // 1/sqrt(512)
#define KVB 32
#define NTILES 64                     // S_/KVB

typedef __attribute__((ext_vector_type(8))) short short8;    // 8 bf16 (4 VGPRs)
typedef __attribute__((ext_vector_type(4))) float floatx4;

static __device__ __forceinline__ unsigned short f2bf(float f) {
    unsigned u = __float_as_uint(f);
    u = u + 0x7FFFu + ((u >> 16) & 1u);   // RNE
    return (unsigned short)(u >> 16);
}
static __device__ __forceinline__ float bf2f(unsigned short h) {
    return __uint_as_float(((unsigned)h) << 16);
}

// ---------------- fused prep: k->bf16 cvt + v/w1/w2 transpose-cvt ----------------
// blocks [0,8192): cvt k (8192*256 lanes * 8 elems = 16M)
// blocks [8192,12288): v transpose  (per batch z: [2048][512] -> [512][2048])
// blocks [12288,12416): w1 transpose ([512][1024] -> [1024][512])
// blocks [12416,12544): w2 transpose ([1024][512] -> [512][1024])
__global__ void prep_kernel(const float* __restrict__ k, unsigned short* __restrict__ kb,
                            const float* __restrict__ v, unsigned short* __restrict__ vt,
                            const float* __restrict__ w1, unsigned short* __restrict__ w1t,
                            const float* __restrict__ w2, unsigned short* __restrict__ w2t) {
    __shared__ float t[64 * 68];
    const int bid = blockIdx.x, tid = threadIdx.x;
    if (bid < 8192) {
        int i = bid * 256 + tid;
        const float4* p = (const float4*)k + (long)i * 2;
        float4 a = p[0], b = p[1];
        union { unsigned short u[8]; uint4 v4; } r;
        r.u[0] = f2bf(a.x); r.u[1] = f2bf(a.y); r.u[2] = f2bf(a.z); r.u[3] = f2bf(a.w);
        r.u[4] = f2bf(b.x); r.u[5] = f2bf(b.y); r.u[6] = f2bf(b.z); r.u[7] = f2bf(b.w);
        ((uint4*)kb)[i] = r.v4;
        return;
    }
    const float* in; unsigned short* out; int R, C, c0, r0;
    if (bid < 12288) {
        int i = bid - 8192;
        int z = i >> 8;                       // 256 tiles per batch
        in = v + (long)z * 2048 * 512; out = vt + (long)z * 512 * 2048;
        R = 2048; C = 512; c0 = (i & 7) * 64; r0 = ((i >> 3) & 31) * 64;
    } else if (bid < 12416) {
        int i = bid - 12288;
        in = w1; out = w1t; R = 512; C = 1024; c0 = (i & 15) * 64; r0 = (i >> 4) * 64;
    } else {
        int i = bid - 12416;
        in = w2; out = w2t; R = 1024; C = 512; c0 = (i & 7) * 64; r0 = (i >> 3) * 64;
    }
    {
        int col4 = (tid & 15) * 4;
        #pragma unroll
        for (int i = 0; i < 4; i++) {
            int row = (tid >> 4) + i * 16;
            float4 vv = *(const float4*)(in + (long)(r0 + row) * C + c0 + col4);
            *(float4*)(&t[row * 68 + col4]) = vv;
        }
    }
    __syncthreads();
    {
        int oc = tid >> 2;            // output row (C index), 0..63
        int ob = (tid & 3) * 16;      // output col base (R index)
        union { unsigned short u[16]; uint4 v4[2]; } r;
        #pragma unroll
        for (int j = 0; j < 16; j++) r.u[j] = f2bf(t[(ob + j) * 68 + oc]);
        uint4* dst = (uint4*)(out + (long)(c0 + oc) * R + r0 + ob);
        dst[0] = r.v4[0]; dst[1] = r.v4[1];
    }
}

// ---------------- flash attention + residual + fused LN1 ----------------
// R1 structure verbatim; R6 delta: pLDS 64x32 shorts with quad-XOR swizzle.
__launch_bounds__(256, 2)
__global__ void attn_kernel(const float* __restrict__ q,             // [B][S][E] fp32
                            const unsigned short* __restrict__ kb,   // [B][S][E] bf16
                            const unsigned short* __restrict__ vt,   // [B][E][S] bf16
                            const float* __restrict__ g1,            // ln1 gamma [E] fp32
                            const float* __restrict__ bb1,           // ln1 beta  [E] fp32
                            unsigned short* __restrict__ xb) {       // [B][S][E] bf16 = LN1(q+attn)
    __shared__ unsigned short kLDS[2][KVB * E_];   // 2 x 32KB, swizzled rows
    __shared__ unsigned short pLDS[64 * 32];       // 4KB, quad-XOR swizzled chunks
    __shared__ float aLDS[64];
    __shared__ float lLDS[64];
    __shared__ float sumLDS[64 * 4];
    __shared__ float sqLDS[64 * 4];
    const int tid = threadIdx.x;
    const int w = tid >> 6, lane = tid & 63, quad = lane >> 4, l16 = lane & 15;
    const int b = blockIdx.x >> 5, q0 = (blockIdx.x & 31) * 64;
    const floatx4 zf = {0.f, 0.f, 0.f, 0.f};

    const unsigned short* kb_b = kb + (long)b * S_ * E_;

    // Q A-frags: A[m=l16][k=quad*8+j], 16 chunks of K=32 over E=512 (fp32 -> bf16)
    short8 aq[16];
    {
        const float* qp = q + (long)(b * S_ + q0 + 16 * w + l16) * E_ + quad * 8;
        #pragma unroll
        for (int kc = 0; kc < 16; kc++) {
            float4 x0 = *(const float4*)(qp + kc * 32);
            float4 x1 = *(const float4*)(qp + kc * 32 + 4);
            short8 t;
            t[0] = (short)f2bf(x0.x); t[1] = (short)f2bf(x0.y);
            t[2] = (short)f2bf(x0.z); t[3] = (short)f2bf(x0.w);
            t[4] = (short)f2bf(x1.x); t[5] = (short)f2bf(x1.y);
            t[6] = (short)f2bf(x1.z); t[7] = (short)f2bf(x1.w);
            aq[kc] = t;
        }
    }

    floatx4 oacc[4][8];   // [qg][nt] : 64q x 128f per wave
    #pragma unroll
    for (int qg = 0; qg < 4; qg++)
        #pragma unroll
        for (int nt = 0; nt < 8; nt++) oacc[qg][nt] = zf;
    float m_[4] = {-INFINITY, -INFINITY, -INFINITY, -INFINITY};
    float l_[4] = {0.f, 0.f, 0.f, 0.f};

    const unsigned short* vbase = vt + (long)(b * E_ + 128 * w + l16) * S_ + quad * 8;

    // prologue: stage K tile 0 into kLDS[0].
    {
        #pragma unroll
        for (int j = 0; j < 8; j++) {
            int row = j * 4 + w;
            const unsigned short* g = kb_b + (long)row * E_ + ((lane * 8) ^ ((row & 7) << 3));
            __builtin_amdgcn_global_load_lds(
                (const __attribute__((address_space(1))) void*)g,
                (__attribute__((address_space(3))) void*)(&kLDS[0][row * E_]), 16, 0, 0);
        }
    }
    __syncthreads();   // implicit vmcnt(0) drain -> tile 0 resident

    for (int t = 0; t < NTILES; t++) {
        const int cur = t & 1;
        const int kt0 = t * KVB;

        // A: issue async stage of tile t+1 into the other buffer.
        if (t + 1 < NTILES) {
            const unsigned short* kb_t = kb_b + (long)(kt0 + KVB) * E_;
            #pragma unroll
            for (int j = 0; j < 8; j++) {
                int row = j * 4 + w;
                const unsigned short* g = kb_t + (long)row * E_ + ((lane * 8) ^ ((row & 7) << 3));
                __builtin_amdgcn_global_load_lds(
                    (const __attribute__((address_space(1))) void*)g,
                    (__attribute__((address_space(3))) void*)(&kLDS[cur ^ 1][row * E_]), 16, 0, 0);
            }
        }

        // B: QK^T from kLDS[cur] (swizzled ds_read_b128)
        floatx4 sacc[2] = {zf, zf};
        const unsigned short* kl = &kLDS[cur][0];
        const int swz = (l16 & 7) << 3;   // (row&7)<<3 for row=l16 and row=16+l16
        #pragma unroll
        for (int kc = 0; kc < 16; kc++) {
            const int cx = (kc * 32 + quad * 8) ^ swz;
            short8 b0 = *(const short8*)(kl + l16 * E_ + cx);
            short8 b1 = *(const short8*)(kl + (16 + l16) * E_ + cx);
            sacc[0] = __builtin_amdgcn_mfma_f32_16x16x32_bf16(aq[kc], b0, sacc[0], 0, 0, 0);
            sacc[1] = __builtin_amdgcn_mfma_f32_16x16x32_bf16(aq[kc], b1, sacc[1], 0, 0, 0);
        }

        // C: online softmax: row m = quad*4+r, col n = l16 / 16+l16
        float rm[4], al[4], P2[2][4], rs[4];
        #pragma unroll
        for (int r = 0; r < 4; r++)
            rm[r] = fmaxf(sacc[0][r], sacc[1][r]) * SCALE;
        #pragma unroll
        for (int off = 1; off < 16; off <<= 1)
            #pragma unroll
            for (int r = 0; r < 4; r++) rm[r] = fmaxf(rm[r], __shfl_xor(rm[r], off));
        #pragma unroll
        for (int r = 0; r < 4; r++) {
            float mn = fmaxf(m_[r], rm[r]);
            al[r] = __expf(m_[r] - mn);
            m_[r] = mn;
            float p0 = __expf(sacc[0][r] * SCALE - mn);
            float p1 = __expf(sacc[1][r] * SCALE - mn);
            P2[0][r] = p0; P2[1][r] = p1;
            rs[r] = p0 + p1;
        }
        #pragma unroll
        for (int off = 1; off < 16; off <<= 1)
            #pragma unroll
            for (int r = 0; r < 4; r++) rs[r] += __shfl_xor(rs[r], off);
        #pragma unroll
        for (int r = 0; r < 4; r++) l_[r] = l_[r] * al[r] + rs[r];
        // P write: row = 16w+quad*4+r, col = nt*16+l16; phys chunk-XOR by quad
        // (= (row>>2)&3). Write banks 2-way (free); read banks exactly even.
        #pragma unroll
        for (int nt = 0; nt < 2; nt++)
            #pragma unroll
            for (int r = 0; r < 4; r++) {
                int row = 16 * w + quad * 4 + r;
                pLDS[row * 32 + (((nt * 2 + (l16 >> 3)) ^ quad) << 3) + (l16 & 7)] = f2bf(P2[nt][r]);
            }
        if (l16 == 0) {
            #pragma unroll
            for (int r = 0; r < 4; r++) aLDS[16 * w + quad * 4 + r] = al[r];
        }
        __syncthreads();   // D: P visible; K tile t+1 staged.

        // F: PV. P A-frag: A[m=l16][k=quad*8+j]; chunk=quad, q4(row)=(l16>>2)&3.
        short8 pf[4];
        #pragma unroll
        for (int qg = 0; qg < 4; qg++)
            pf[qg] = *(const short8*)(&pLDS[(qg * 16 + l16) * 32 + ((quad ^ ((l16 >> 2) & 3)) << 3)]);
        float av[4][4];
        #pragma unroll
        for (int qg = 0; qg < 4; qg++)
            #pragma unroll
            for (int r = 0; r < 4; r++) av[qg][r] = aLDS[qg * 16 + quad * 4 + r];
        #pragma unroll
        for (int qg = 0; qg < 4; qg++)
            #pragma unroll
            for (int nt = 0; nt < 8; nt++)
                #pragma unroll
                for (int r = 0; r < 4; r++) oacc[qg][nt][r] *= av[qg][r];
        const unsigned short* vtt = vbase + kt0;
        #pragma unroll
        for (int nt = 0; nt < 8; nt++) {
            short8 vf = *(const short8*)(vtt + (long)nt * 16 * S_);
            #pragma unroll
            for (int qg = 0; qg < 4; qg++)
                oacc[qg][nt] = __builtin_amdgcn_mfma_f32_16x16x32_bf16(pf[qg], vf, oacc[qg][nt], 0, 0, 0);
        }
        __syncthreads();   // G: all reads of kLDS[cur]/pLDS done before next writes
    }

    // epilogue: y = q + O/l (fp32), fused LN1
    if (l16 == 0) {
        #pragma unroll
        for (int r = 0; r < 4; r++) lLDS[16 * w + quad * 4 + r] = l_[r];
    }
    __syncthreads();
    float lv[4][4];
    #pragma unroll
    for (int qg = 0; qg < 4; qg++)
        #pragma unroll
        for (int r = 0; r < 4; r++) lv[qg][r] = 1.f / lLDS[qg * 16 + quad * 4 + r];
    float ps[4][4], pq2[4][4];
    #pragma unroll
    for (int qg = 0; qg < 4; qg++)
        #pragma unroll
        for (int r = 0; r < 4; r++) { ps[qg][r] = 0.f; pq2[qg][r] = 0.f; }
    #pragma unroll
    for (int qg = 0; qg < 4; qg++)
        #pragma unroll
        for (int nt = 0; nt < 8; nt++)
            #pragma unroll
            for (int r = 0; r < 4; r++) {
                int qrow = q0 + qg * 16 + quad * 4 + r;
                int feat = 128 * w + nt * 16 + l16;
                float y = q[(long)(b * S_ + qrow) * E_ + feat] + oacc[qg][nt][r] * lv[qg][r];
                oacc[qg][nt][r] = y;
                ps[qg][r] += y; pq2[qg][r] += y * y;
            }
    #pragma unroll
    for (int off = 1; off < 16; off <<= 1)
        #pragma unroll
        for (int qg = 0; qg < 4; qg++)
            #pragma unroll
            for (int r = 0; r < 4; r++) {
                ps[qg][r] += __shfl_xor(ps[qg][r], off);
                pq2[qg][r] += __shfl_xor(pq2[qg][r], off);
            }
    if (l16 == 0) {
        #pragma unroll
        for (int qg = 0; qg < 4; qg++)
            #pragma unroll
            for (int r = 0; r < 4; r++) {
                int row = qg * 16 + quad * 4 + r;
                sumLDS[row * 4 + w] = ps[qg][r];
                sqLDS[row * 4 + w] = pq2[qg][r];
            }
    }
    __syncthreads();
    float mu[4][4], rstd[4][4];
    #pragma unroll
    for (int qg = 0; qg < 4; qg++)
        #pragma unroll
        for (int r = 0; r < 4; r++) {
            int row = qg * 16 + quad * 4 + r;
            float s = (sumLDS[row * 4 + 0] + sumLDS[row * 4 + 1]) + (sumLDS[row * 4 + 2] + sumLDS[row * 4 + 3]);
            float s2 = (sqLDS[row * 4 + 0] + sqLDS[row * 4 + 1]) + (sqLDS[row * 4 + 2] + sqLDS[row * 4 + 3]);
            float mean = s * (1.f / E_);
            float var = s2 * (1.f / E_) - mean * mean;
            mu[qg][r] = mean;
            rstd[qg][r] = rsqrtf(fmaxf(var, 0.f) + 1e-5f);
        }
    float gv[8], bv[8];
    #pragma unroll
    for (int nt = 0; nt < 8; nt++) {
        int feat = 128 * w + nt * 16 + l16;
        gv[nt] = g1[feat]; bv[nt] = bb1[feat];
    }
    #pragma unroll
    for (int qg = 0; qg < 4; qg++)
        #pragma unroll
        for (int nt = 0; nt < 8; nt++)
            #pragma unroll
            for (int r = 0; r < 4; r++) {
                int qrow = q0 + qg * 16 + quad * 4 + r;
                int feat = 128 * w + nt * 16 + l16;
                xb[(long)(b * S_ + qrow) * E_ + feat] =
                    f2bf((oacc[qg][nt][r] - mu[qg][r]) * rstd[qg][r] * gv[nt] + bv[nt]);
            }
}

// ---------------- fused FFN + residual + LN3 (R4 version, verbatim) ----------------
// Block = 64 rows, 8 waves (512 thr). ldsX = X_block (64KB, attn-kLDS swizzle,
// staged once, reused as gemm1-A and LN3 residual). 4 chunks of H=256:
//   phase1: wave w computes h[64][32w..32w+32) from ldsX + W1t(global),
//           +b1, exact GELU, write swizzled ldsH[c&1].
//   barrier (1 per chunk; ldsH double-buffered).
//   phase2: acc2[4][4] += h_chunk @ W2t[64w..64w+64) (B direct-global).
// Epilogue: +b2 +resid(ldsX), LN3 in-block, fp32 out.
__launch_bounds__(512, 2)
__global__ void ffn_ln3_kernel(const unsigned short* __restrict__ X,    // xb [M][512] bf16
                               const unsigned short* __restrict__ W1t,  // [1024][512] bf16
                               const float* __restrict__ b1,            // [1024]
                               const unsigned short* __restrict__ W2t,  // [512][1024] bf16
                               const float* __restrict__ b2,            // [512]
                               const float* __restrict__ g3, const float* __restrict__ bb3,
                               float* __restrict__ Out) {               // [M][512] fp32
    __shared__ unsigned short ldsX[64 * 512];      // 64 KB, swizzled rows (8-short chunks)
    __shared__ unsigned short ldsH[2][64 * 256];   // 2 x 32 KB, swizzled rows
    __shared__ float sumLDS[64 * 8], sqLDS[64 * 8];
    const int tid = threadIdx.x, w = tid >> 6, lane = tid & 63, quad = lane >> 4, l16 = lane & 15;
    const long m0 = (long)blockIdx.x * 64;
    const floatx4 zf = {0.f, 0.f, 0.f, 0.f};
    floatx4 acc2[4][4];   // [mt][nt]: 64 rows x 64 out-cols (n = 64w + nt*16 + l16)
    #pragma unroll
    for (int i = 0; i < 4; i++)
        #pragma unroll
        for (int j = 0; j < 4; j++) acc2[i][j] = zf;

    // stage X_block: wave w stages rows 8w..8w+7 (linear LDS dest, pre-swizzled src)
    #pragma unroll
    for (int j = 0; j < 8; j++) {
        int row = w * 8 + j;
        const unsigned short* g = X + (m0 + row) * 512 + ((lane * 8) ^ ((row & 7) << 3));
        __builtin_amdgcn_global_load_lds(
            (const __attribute__((address_space(1))) void*)g,
            (__attribute__((address_space(3))) void*)(&ldsX[row * 512]), 16, 0, 0);
    }
    __syncthreads();   // X resident

    const int swzx = (l16 & 7) << 3;
    for (int c = 0; c < 4; c++) {
        // ---- phase 1: h[64][256-chunk], wave slice n-in-chunk = 32w..32w+31 ----
        floatx4 acc1[4][2];
        #pragma unroll
        for (int mt = 0; mt < 4; mt++) { acc1[mt][0] = zf; acc1[mt][1] = zf; }
        const unsigned short* w1p = W1t + (long)(c * 256 + 32 * w + l16) * 512 + quad * 8;
        #pragma unroll
        for (int kc = 0; kc < 16; kc++) {
            short8 bf0 = *(const short8*)(w1p + kc * 32);
            short8 bf1 = *(const short8*)(w1p + 16 * 512 + kc * 32);
            const int cx = (kc * 32 + quad * 8) ^ swzx;
            #pragma unroll
            for (int mt = 0; mt < 4; mt++) {
                short8 af = *(const short8*)(&ldsX[(mt * 16 + l16) * 512 + cx]);
                acc1[mt][0] = __builtin_amdgcn_mfma_f32_16x16x32_bf16(af, bf0, acc1[mt][0], 0, 0, 0);
                acc1[mt][1] = __builtin_amdgcn_mfma_f32_16x16x32_bf16(af, bf1, acc1[mt][1], 0, 0, 0);
            }
        }
        unsigned short* hb = &ldsH[c & 1][0];
        #pragma unroll
        for (int nt = 0; nt < 2; nt++) {
            int hn = 32 * w + nt * 16 + l16;        // col in chunk, 0..255
            float b1v = b1[c * 256 + hn];
            int hc8 = hn >> 3, hoff = hn & 7;
            #pragma unroll
            for (int mt = 0; mt < 4; mt++)
                #pragma unroll
                for (int r = 0; r < 4; r++) {
                    int row = mt * 16 + quad * 4 + r;
                    float v = acc1[mt][nt][r] + b1v;
                    v = 0.5f * v * (1.f + erff(v * 0.70710678118f));   // exact GELU
                    hb[row * 256 + ((hc8 ^ (row & 7)) << 3) + hoff] = f2bf(v);
                }
        }
        __syncthreads();   // h chunk visible; prior readers of this buf done

        // ---- phase 2: acc2 += h_chunk @ W2t[ n=64w.. ][ k=c*256.. ] ----
        const unsigned short* hrd = &ldsH[c & 1][0];
        const unsigned short* w2p = W2t + (long)(64 * w + l16) * 1024 + c * 256 + quad * 8;
        #pragma unroll
        for (int kc = 0; kc < 8; kc++) {
            short8 af[4], bf[4];
            const int hphys = ((kc * 4 + quad) ^ (l16 & 7)) << 3;
            #pragma unroll
            for (int mt = 0; mt < 4; mt++)
                af[mt] = *(const short8*)(&hrd[(mt * 16 + l16) * 256 + hphys]);
            #pragma unroll
            for (int nt = 0; nt < 4; nt++)
                bf[nt] = *(const short8*)(w2p + (long)nt * 16 * 1024 + kc * 32);
            #pragma unroll
            for (int mt = 0; mt < 4; mt++)
                #pragma unroll
                for (int nt = 0; nt < 4; nt++)
                    acc2[mt][nt] = __builtin_amdgcn_mfma_f32_16x16x32_bf16(af[mt], bf[nt], acc2[mt][nt], 0, 0, 0);
        }
    }

    // ---- epilogue: v = acc2 + b2 + resid(ldsX); LN3 in-block ----
    float ps[4][4], pq2[4][4];
    #pragma unroll
    for (int mt = 0; mt < 4; mt++)
        #pragma unroll
        for (int r = 0; r < 4; r++) { ps[mt][r] = 0.f; pq2[mt][r] = 0.f; }
    #pragma unroll
    for (int nt = 0; nt < 4; nt++) {
        int n = 64 * w + nt * 16 + l16;
        float bv = b2[n];
        int nc8 = n >> 3, noff = n & 7;
        #pragma unroll
        for (int mt = 0; mt < 4; mt++)
            #pragma unroll
            for (int r = 0; r < 4; r++) {
                int row = mt * 16 + quad * 4 + r;
                float resid = bf2f(ldsX[row * 512 + ((nc8 ^ (row & 7)) << 3) + noff]);
                float v = acc2[mt][nt][r] + bv + resid;
                acc2[mt][nt][r] = v;
                ps[mt][r] += v; pq2[mt][r] += v * v;
            }
    }
    #pragma unroll
    for (int off = 1; off < 16; off <<= 1)
        #pragma unroll
        for (int mt = 0; mt < 4; mt++)
            #pragma unroll
            for (int r = 0; r < 4; r++) {
                ps[mt][r] += __shfl_xor(ps[mt][r], off);
                pq2[mt][r] += __shfl_xor(pq2[mt][r], off);
            }
    if (l16 == 0) {
        #pragma unroll
        for (int mt = 0; mt < 4; mt++)
            #pragma unroll
            for (int r = 0; r < 4; r++) {
                int row = mt * 16 + quad * 4 + r;
                sumLDS[row * 8 + w] = ps[mt][r];
                sqLDS[row * 8 + w] = pq2[mt][r];
            }
    }
    __syncthreads();
    float mu[4][4], rstd[4][4];
    #pragma unroll
    for (int mt = 0; mt < 4; mt++)
        #pragma unroll
        for (int r = 0; r < 4; r++) {
            int row = mt * 16 + quad * 4 + r;
            float s = 0.f, s2 = 0.f;
            #pragma unroll
            for (int ww = 0; ww < 8; ww++) { s += sumLDS[row * 8 + ww]; s2 += sqLDS[row * 8 + ww]; }
            float mean = s * (1.f / E_);
            float var = s2 * (1.f / E_) - mean * mean;
            mu[mt][r] = mean;
            rstd[mt][r] = rsqrtf(fmaxf(var, 0.f) + 1e-5f);
        }
    #pragma unroll
    for (int nt = 0; nt < 4; nt++) {
        int n = 64 * w + nt * 16 + l16;
        float gv = g3[n], bv3 = bb3[n];
        #pragma unroll
        for (int mt = 0; mt < 4; mt++) {
            long m = m0 + mt * 16 + quad * 4;
            #pragma unroll
            for (int r = 0; r < 4; r++)
                Out[(m + r) * E_ + n] =
                    (acc2[mt][nt][r] - mu[mt][r]) * rstd[mt][r] * gv + bv3;
        }
    }
}

extern "C" void kernel_launch(void* const* d_in, const int* in_sizes, int n_in,
                              void* d_out, int out_size, void* d_ws, size_t ws_size,
                              hipStream_t stream) {
    const float* q    = (const float*)d_in[0];
    const float* k    = (const float*)d_in[1];
    const float* v    = (const float*)d_in[2];
    const float* ln1g = (const float*)d_in[3];
    const float* ln1b = (const float*)d_in[4];
    const float* w1   = (const float*)d_in[5];
    const float* b1   = (const float*)d_in[6];
    const float* w2   = (const float*)d_in[7];
    const float* b2   = (const float*)d_in[8];
    const float* ln3g = (const float*)d_in[9];
    const float* ln3b = (const float*)d_in[10];

    // Workspace, 98 MB total (phase-aliased):
    //  [0,32M):   kb  (prep -> attn)
    //  [32M,64M): vt  (prep -> attn)
    //  [64M,96M): xb  (attn -> ffn)
    //  [96M,97M): w1t   [97M,98M): w2t
    char* ws = (char*)d_ws;
    unsigned short* kb  = (unsigned short*)(ws);
    unsigned short* vt  = (unsigned short*)(ws + 33554432);
    unsigned short* xb  = (unsigned short*)(ws + 67108864);
    unsigned short* w1t = (unsigned short*)(ws + 100663296);
    unsigned short* w2t = (unsigned short*)(ws + 101711872);
    float* ob = (float*)d_out;                                   // fp32 output

    prep_kernel<<<12544, 256, 0, stream>>>(k, kb, v, vt, w1, w1t, w2, w2t);
    attn_kernel<<<512, 256, 0, stream>>>(q, kb, vt, ln1g, ln1b, xb);
    ffn_ln3_kernel<<<512, 512, 0, stream>>>(xb, w1t, b1, w2t, b2, ln3g, ln3b, ob);
}